// Round 1
// baseline (1242.649 us; speedup 1.0000x reference)
//
#include <hip/hip_runtime.h>

// OrthogonalButterfly: 20 layers of Givens rotations on pairs (j, j+512)
// followed by a perfect shuffle (dest = rotl1(src) on the 10-bit index).
// In the substituted domain y_d[i] = x_d[rotl_d(i)] the network is an
// in-place butterfly: layer d pairs indices differing in bit b=9-(d%10),
// coefficient index j = rotl_{d%10}(i with bit b cleared). rotl^20 == id
// on 10 bits, so y_20 == x_20: no physical permutation anywhere.

#define WIDTH   1024
#define DEPTH   20
#define NROWS   32768
#define TILE    8          // rows per wave, held in registers (8*16 VGPR)

// ---------------------------------------------------------------------------
// Setup: bake per-(layer, reg, lane) coefficient pairs (cos, +-sin), sign
// folded per element, gathered into the exact order the main kernel reads.
// tab[(d*16 + r)*64 + lane] = (c, s_eff).  Size: 20*16*64*8 B = 160 KiB.
// ---------------------------------------------------------------------------
__global__ void bfly_setup(const float* __restrict__ params,
                           float2* __restrict__ tab) {
  int tid = blockIdx.x * blockDim.x + threadIdx.x;
  if (tid >= DEPTH * 16 * 64) return;
  int L = tid & 63;          // lane   = i[7:2]
  int r = (tid >> 6) & 15;   // reg    = {i[9:8], i[1:0]}
  int d = tid >> 10;         // layer
  int i = ((r >> 2) << 8) | (L << 2) | (r & 3);   // reconstruct element index
  int rot = d % 10;
  int b = 9 - rot;           // butterfly bit for this layer
  int m = 1 << b;
  int i0 = i & ~m;
  int j = rot ? (((i0 << rot) | (i0 >> (10 - rot))) & 1023) : i0;  // j < 512
  float theta = params[j * DEPTH + d];   // params is (512, 20) row-major
  float c = cosf(theta);
  float s = sinf(theta);
  if (i & m) s = -s;         // "x1" element: c*self - s*partner
  tab[(d * 16 + r) * 64 + L] = make_float2(c, s);
}

// ---------------------------------------------------------------------------
// Main: one wave per 8 rows. Layout: lane = i[7:2], reg = {i[9:8], i[1:0]}
//  -> bits 9,8,1,0 are register-local pairs; bits 7..2 are shfl_xor.
//  -> float4 global loads/stores (16 B/lane).
// ---------------------------------------------------------------------------
__global__ __launch_bounds__(256, 2)
void bfly_main(const float* __restrict__ X,
               const float2* __restrict__ tab,
               float* __restrict__ out) {
  const int lane = threadIdx.x & 63;
  const int wid  = blockIdx.x * (blockDim.x >> 6) + (threadIdx.x >> 6);
  const long base = (long)wid * TILE * WIDTH;

  float y[TILE][16];

  // ---- load 8 rows, 4 float4 each ----
  const float* xp = X + base;
#pragma unroll
  for (int t = 0; t < TILE; ++t) {
#pragma unroll
    for (int k = 0; k < 4; ++k) {
      float4 v = *reinterpret_cast<const float4*>(
          xp + t * WIDTH + k * 256 + lane * 4);
      y[t][k * 4 + 0] = v.x;
      y[t][k * 4 + 1] = v.y;
      y[t][k * 4 + 2] = v.z;
      y[t][k * 4 + 3] = v.w;
    }
  }

  // ---- 20 layers, fully unrolled; all branches fold at compile time ----
#pragma unroll
  for (int d = 0; d < DEPTH; ++d) {
    const int b = 9 - (d % 10);
    float2 cs[16];
#pragma unroll
    for (int r = 0; r < 16; ++r)
      cs[r] = tab[(d * 16 + r) * 64 + lane];

    if (b >= 8 || b <= 1) {
      // register-local pair: reg bit 3<->i9, 2<->i8, 1<->i1, 0<->i0
      const int rm = (b == 9) ? 8 : (b == 8) ? 4 : (b == 1) ? 2 : 1;
#pragma unroll
      for (int t = 0; t < TILE; ++t) {
#pragma unroll
        for (int r = 0; r < 16; ++r) {
          if (!(r & rm)) {
            const int r2 = r | rm;
            float a0 = y[t][r];
            float a1 = y[t][r2];
            y[t][r]  = cs[r].x  * a0 + cs[r].y  * a1;  // s baked +sin
            y[t][r2] = cs[r2].x * a1 + cs[r2].y * a0;  // s baked -sin
          }
        }
      }
    } else {
      // cross-lane pair: lane bit (b-2)
      const int lm = 1 << (b - 2);
#pragma unroll
      for (int t = 0; t < TILE; ++t) {
#pragma unroll
        for (int r = 0; r < 16; ++r) {
          float p = __shfl_xor(y[t][r], lm, 64);
          y[t][r] = cs[r].x * y[t][r] + cs[r].y * p;
        }
      }
    }
  }

  // ---- store (y_20 == x_20: no permutation) ----
  float* op = out + base;
#pragma unroll
  for (int t = 0; t < TILE; ++t) {
#pragma unroll
    for (int k = 0; k < 4; ++k) {
      float4 v;
      v.x = y[t][k * 4 + 0];
      v.y = y[t][k * 4 + 1];
      v.z = y[t][k * 4 + 2];
      v.w = y[t][k * 4 + 3];
      *reinterpret_cast<float4*>(op + t * WIDTH + k * 256 + lane * 4) = v;
    }
  }
}

extern "C" void kernel_launch(void* const* d_in, const int* in_sizes, int n_in,
                              void* d_out, int out_size, void* d_ws, size_t ws_size,
                              hipStream_t stream) {
  const float* X      = (const float*)d_in[0];
  const float* params = (const float*)d_in[1];
  float* out          = (float*)d_out;
  float2* tab         = (float2*)d_ws;   // needs 160 KiB of ws

  // 1) bake coefficient table (re-done every call; ws is re-poisoned)
  bfly_setup<<<(DEPTH * 16 * 64 + 255) / 256, 256, 0, stream>>>(params, tab);

  // 2) butterfly: 32768 rows / 8 rows-per-wave = 4096 waves = 1024 blocks
  bfly_main<<<(NROWS / TILE) / 4, 256, 0, stream>>>(X, tab, out);
}

// Round 2
// 463.017 us; speedup vs baseline: 2.6838x; 2.6838x over previous
//
#include <hip/hip_runtime.h>

// OrthogonalButterfly: 20 layers of Givens rotations on pairs (j, j+512)
// followed by a perfect shuffle (dest = rotl1(src) on the 10-bit index).
// In the substituted domain y_d[i] = x_d[rotl_d(i)] the network is an
// in-place butterfly: layer d pairs indices differing in bit b=9-(d%10),
// coefficient index j = rotl_{d%10}(i with bit b cleared). rotl^20 == id
// on 10 bits, so y_20 == x_20: no physical permutation anywhere.
//
// R1 lesson: the 20-layer loop must NOT rely on #pragma unroll — hipcc left
// it rolled, `rm` became runtime, y[t][r|rm] became runtime-indexed, and the
// whole y array went to scratch (VGPR=72, hbm_bytes=5.4GB of scratch traffic,
// 20x over-fetch). Fix: template<int d> layers with constexpr b/rm/lm so all
// register indices are compile-time constants by construction.

#define WIDTH   1024
#define DEPTH   20
#define NROWS   32768
#define TILE    8          // rows per wave, held in registers (8*16 VGPR)

// ---------------------------------------------------------------------------
// Setup: bake per-(layer, reg, lane) coefficient pairs (cos, +-sin), sign
// folded per element, gathered into the exact order the main kernel reads.
// tab[(d*16 + r)*64 + lane] = (c, s_eff).  Size: 20*16*64*8 B = 160 KiB.
// ---------------------------------------------------------------------------
__global__ void bfly_setup(const float* __restrict__ params,
                           float2* __restrict__ tab) {
  int tid = blockIdx.x * blockDim.x + threadIdx.x;
  if (tid >= DEPTH * 16 * 64) return;
  int L = tid & 63;          // lane   = i[7:2]
  int r = (tid >> 6) & 15;   // reg    = {i[9:8], i[1:0]}
  int d = tid >> 10;         // layer
  int i = ((r >> 2) << 8) | (L << 2) | (r & 3);   // reconstruct element index
  int rot = d % 10;
  int b = 9 - rot;           // butterfly bit for this layer
  int m = 1 << b;
  int i0 = i & ~m;
  int j = rot ? (((i0 << rot) | (i0 >> (10 - rot))) & 1023) : i0;  // j < 512
  float theta = params[j * DEPTH + d];   // params is (512, 20) row-major
  float c = cosf(theta);
  float s = sinf(theta);
  if (i & m) s = -s;         // "x1" element: c*self - s*partner
  tab[(d * 16 + r) * 64 + L] = make_float2(c, s);
}

// ---------------------------------------------------------------------------
// One butterfly layer, all constants compile-time.
// ---------------------------------------------------------------------------
template <int d>
__device__ __forceinline__ void bfly_layer(float (&y)[TILE][16],
                                           const float2* __restrict__ tab,
                                           int lane) {
  constexpr int b = 9 - (d % 10);

  float2 cs[16];
#pragma unroll
  for (int r = 0; r < 16; ++r)
    cs[r] = tab[(d * 16 + r) * 64 + lane];

  if constexpr (b >= 8 || b <= 1) {
    // register-local pair: reg bit 3<->i9, 2<->i8, 1<->i1, 0<->i0
    constexpr int rm = (b == 9) ? 8 : (b == 8) ? 4 : (b == 1) ? 2 : 1;
#pragma unroll
    for (int t = 0; t < TILE; ++t) {
#pragma unroll
      for (int r = 0; r < 16; ++r) {
        if constexpr (true) {
          if ((r & rm) == 0) {            // folds at unroll: r,rm const
            const int r2 = r | rm;        // compile-time after unroll
            float a0 = y[t][r];
            float a1 = y[t][r2];
            y[t][r]  = cs[r].x  * a0 + cs[r].y  * a1;  // s baked +sin
            y[t][r2] = cs[r2].x * a1 + cs[r2].y * a0;  // s baked -sin
          }
        }
      }
    }
  } else {
    // cross-lane pair: lane bit (b-2), compile-time xor mask
    constexpr int lm = 1 << (b - 2);
#pragma unroll
    for (int t = 0; t < TILE; ++t) {
#pragma unroll
      for (int r = 0; r < 16; ++r) {
        float p = __shfl_xor(y[t][r], lm, 64);
        y[t][r] = cs[r].x * y[t][r] + cs[r].y * p;
      }
    }
  }
}

// ---------------------------------------------------------------------------
// Main: one wave per 8 rows. Layout: lane = i[7:2], reg = {i[9:8], i[1:0]}
//  -> bits 9,8,1,0 are register-local pairs; bits 7..2 are shfl_xor.
//  -> float4 global loads/stores (16 B/lane).
// ---------------------------------------------------------------------------
__global__ __launch_bounds__(256, 2)
void bfly_main(const float* __restrict__ X,
               const float2* __restrict__ tab,
               float* __restrict__ out) {
  const int lane = threadIdx.x & 63;
  const int wid  = blockIdx.x * (blockDim.x >> 6) + (threadIdx.x >> 6);
  const long base = (long)wid * TILE * WIDTH;

  float y[TILE][16];

  // ---- load 8 rows, 4 float4 each ----
  const float* xp = X + base;
#pragma unroll
  for (int t = 0; t < TILE; ++t) {
#pragma unroll
    for (int k = 0; k < 4; ++k) {
      float4 v = *reinterpret_cast<const float4*>(
          xp + t * WIDTH + k * 256 + lane * 4);
      y[t][k * 4 + 0] = v.x;
      y[t][k * 4 + 1] = v.y;
      y[t][k * 4 + 2] = v.z;
      y[t][k * 4 + 3] = v.w;
    }
  }

  // ---- 20 layers, each a separate instantiation with constexpr constants --
  bfly_layer<0>(y, tab, lane);
  bfly_layer<1>(y, tab, lane);
  bfly_layer<2>(y, tab, lane);
  bfly_layer<3>(y, tab, lane);
  bfly_layer<4>(y, tab, lane);
  bfly_layer<5>(y, tab, lane);
  bfly_layer<6>(y, tab, lane);
  bfly_layer<7>(y, tab, lane);
  bfly_layer<8>(y, tab, lane);
  bfly_layer<9>(y, tab, lane);
  bfly_layer<10>(y, tab, lane);
  bfly_layer<11>(y, tab, lane);
  bfly_layer<12>(y, tab, lane);
  bfly_layer<13>(y, tab, lane);
  bfly_layer<14>(y, tab, lane);
  bfly_layer<15>(y, tab, lane);
  bfly_layer<16>(y, tab, lane);
  bfly_layer<17>(y, tab, lane);
  bfly_layer<18>(y, tab, lane);
  bfly_layer<19>(y, tab, lane);

  // ---- store (y_20 == x_20: no permutation) ----
  float* op = out + base;
#pragma unroll
  for (int t = 0; t < TILE; ++t) {
#pragma unroll
    for (int k = 0; k < 4; ++k) {
      float4 v;
      v.x = y[t][k * 4 + 0];
      v.y = y[t][k * 4 + 1];
      v.z = y[t][k * 4 + 2];
      v.w = y[t][k * 4 + 3];
      *reinterpret_cast<float4*>(op + t * WIDTH + k * 256 + lane * 4) = v;
    }
  }
}

extern "C" void kernel_launch(void* const* d_in, const int* in_sizes, int n_in,
                              void* d_out, int out_size, void* d_ws, size_t ws_size,
                              hipStream_t stream) {
  const float* X      = (const float*)d_in[0];
  const float* params = (const float*)d_in[1];
  float* out          = (float*)d_out;
  float2* tab         = (float2*)d_ws;   // needs 160 KiB of ws

  // 1) bake coefficient table (re-done every call; ws is re-poisoned)
  bfly_setup<<<(DEPTH * 16 * 64 + 255) / 256, 256, 0, stream>>>(params, tab);

  // 2) butterfly: 32768 rows / 8 rows-per-wave = 4096 waves = 1024 blocks
  bfly_main<<<(NROWS / TILE) / 4, 256, 0, stream>>>(X, tab, out);
}